// Round 1
// baseline (442.090 us; speedup 1.0000x reference)
//
#include <hip/hip_runtime.h>
#include <stdint.h>

typedef __bf16 bf16;
typedef __attribute__((ext_vector_type(8))) __bf16 bf16x8;
typedef __attribute__((ext_vector_type(4))) __bf16 bf16x4;
typedef __attribute__((ext_vector_type(4))) float f32x4;

#define DEVFN static __device__ __forceinline__

// async global->LDS, 16B per lane, dest = uniform base + lane*16
DEVFN void gload16(const bf16* g, char* l) {
  __builtin_amdgcn_global_load_lds(
      (const __attribute__((address_space(1))) void*)g,
      (__attribute__((address_space(3))) void*)l, 16, 0, 0);
}

// XOR-swizzled LDS byte offset for a [rows][64 bf16] tile (128B rows).
// physical = row*128 + (kbyte ^ ((row&7)<<4)); matched on write via
// pre-swizzled global source column (global_load_lds writes linearly).
DEVFN int swz(int row, int kb) { return row * 128 + (kb ^ ((row & 7) << 4)); }

DEVFN float redmax16(float v) {
  v = fmaxf(v, __shfl_xor(v, 1));
  v = fmaxf(v, __shfl_xor(v, 2));
  v = fmaxf(v, __shfl_xor(v, 4));
  v = fmaxf(v, __shfl_xor(v, 8));
  return v;
}
DEVFN float redsum16(float v) {
  v += __shfl_xor(v, 1);
  v += __shfl_xor(v, 2);
  v += __shfl_xor(v, 4);
  v += __shfl_xor(v, 8);
  return v;
}

// ---------------- prep: fp32 -> bf16 + weight transposes --------------------
__global__ __launch_bounds__(256) void prep_kernel(
    const float* __restrict__ x, const float* __restrict__ Wq,
    const float* __restrict__ Wk, const float* __restrict__ Wv,
    const float* __restrict__ Wp, bf16* __restrict__ xb,
    bf16* __restrict__ Wt, bf16* __restrict__ Wpt) {
  const int64_t tid = blockIdx.x * 256LL + threadIdx.x;
  const int64_t stride = (int64_t)gridDim.x * 256LL;
  for (int64_t i = tid; i < (8192LL * 512) / 4; i += stride) {
    float4 v = ((const float4*)x)[i];
    bf16x4 o = {(bf16)v.x, (bf16)v.y, (bf16)v.z, (bf16)v.w};
    ((bf16x4*)xb)[i] = o;
  }
  // Wt[c][k] = W[k][c%512], c in [0,1536): Wq|Wk|Wv stacked, transposed
  for (int64_t i = tid; i < 1536LL * 512; i += stride) {
    int c = (int)(i >> 9), k = (int)(i & 511);
    int wsel = c >> 9, cc = c & 511;
    const float* W = wsel == 0 ? Wq : (wsel == 1 ? Wk : Wv);
    Wt[i] = (bf16)W[k * 512 + cc];
  }
  for (int64_t i = tid; i < 512LL * 512; i += stride) {
    int c = (int)(i >> 9), k = (int)(i & 511);
    Wpt[i] = (bf16)Wp[k * 512 + c];
  }
}

// ---------------- shared 128x128 bf16 GEMM mainloop (K=512, BK=64) ----------
DEVFN void gemm_main(const bf16* __restrict__ A, const bf16* __restrict__ B,
                     int rowA0, int rowB0, char* sA, char* sB, f32x4 acc[4][4],
                     int wr, int wc, int lane, int w) {
#pragma unroll
  for (int m = 0; m < 4; m++)
#pragma unroll
    for (int n = 0; n < 4; n++) acc[m][n] = (f32x4){0.f, 0.f, 0.f, 0.f};
  const int lr = lane >> 3;                 // row within 8-row chunk
  const int kswz = 8 * ((lane & 7) ^ lr);   // pre-swizzled source column (elems)
  for (int k0 = 0; k0 < 512; k0 += 64) {
#pragma unroll
    for (int j = 0; j < 4; j++) {
      const int c = w * 4 + j;  // chunk 0..15, 8 rows each
      gload16(A + (rowA0 + c * 8 + lr) * 512 + k0 + kswz, sA + c * 1024);
      gload16(B + (rowB0 + c * 8 + lr) * 512 + k0 + kswz, sB + c * 1024);
    }
    __syncthreads();
    bf16x8 af[4][2], bfv[4][2];
#pragma unroll
    for (int m = 0; m < 4; m++)
#pragma unroll
      for (int kk = 0; kk < 2; kk++) {
        af[m][kk] = *(const bf16x8*)(sA + swz(wr * 64 + m * 16 + (lane & 15),
                                              kk * 64 + (lane >> 4) * 16));
        bfv[m][kk] = *(const bf16x8*)(sB + swz(wc * 64 + m * 16 + (lane & 15),
                                               kk * 64 + (lane >> 4) * 16));
      }
#pragma unroll
    for (int m = 0; m < 4; m++)
#pragma unroll
      for (int n = 0; n < 4; n++)
#pragma unroll
        for (int kk = 0; kk < 2; kk++)
          acc[m][n] = __builtin_amdgcn_mfma_f32_16x16x32_bf16(
              af[m][kk], bfv[n][kk], acc[m][n], 0, 0, 0);
    __syncthreads();
  }
}

// ---------------- QKV projection ------------------------------------------
__global__ __launch_bounds__(256) void qkv_gemm(
    const bf16* __restrict__ xb, const bf16* __restrict__ Wt,
    const float* __restrict__ bq, const float* __restrict__ bk,
    const float* __restrict__ bv, bf16* __restrict__ Qb, bf16* __restrict__ Kb,
    bf16* __restrict__ Vt) {
  __shared__ __align__(128) char sA[16384];
  __shared__ __align__(128) char sB[16384];
  const int lane = threadIdx.x & 63, w = threadIdx.x >> 6;
  const int wr = w >> 1, wc = w & 1;
  const int rowA0 = blockIdx.y * 128;
  const int colB0 = blockIdx.x * 128;
  f32x4 acc[4][4];
  gemm_main(xb, Wt, rowA0, colB0, sA, sB, acc, wr, wc, lane, w);
  const int which = colB0 >> 9;  // 0=Q 1=K 2=V
  const int cc0 = colB0 & 511;
  const float* bias = which == 0 ? bq : (which == 1 ? bk : bv);
#pragma unroll
  for (int m = 0; m < 4; m++)
#pragma unroll
    for (int n = 0; n < 4; n++)
#pragma unroll
      for (int r = 0; r < 4; r++) {
        int row = rowA0 + wr * 64 + m * 16 + (lane >> 4) * 4 + r;
        int col = cc0 + wc * 64 + n * 16 + (lane & 15);
        float v = acc[m][n][r] + bias[col];
        if (which == 0) {
          Qb[(int64_t)row * 512 + col] = (bf16)v;
        } else if (which == 1) {
          Kb[(int64_t)row * 512 + col] = (bf16)v;
        } else {
          int b = row >> 12, nn = row & 4095;
          int hh = col >> 6, e = col & 63;
          Vt[(((int64_t)(b * 8 + hh)) * 64 + e) * 4096 + nn] = (bf16)v;
        }
      }
}

// ---------------- output projection (fp32 out) ----------------------------
__global__ __launch_bounds__(256) void out_gemm(const bf16* __restrict__ Ob,
                                                const bf16* __restrict__ Wpt,
                                                const float* __restrict__ bp,
                                                float* __restrict__ out) {
  __shared__ __align__(128) char sA[16384];
  __shared__ __align__(128) char sB[16384];
  const int lane = threadIdx.x & 63, w = threadIdx.x >> 6;
  const int wr = w >> 1, wc = w & 1;
  const int rowA0 = blockIdx.y * 128;
  const int colB0 = blockIdx.x * 128;
  f32x4 acc[4][4];
  gemm_main(Ob, Wpt, rowA0, colB0, sA, sB, acc, wr, wc, lane, w);
#pragma unroll
  for (int m = 0; m < 4; m++)
#pragma unroll
    for (int n = 0; n < 4; n++)
#pragma unroll
      for (int r = 0; r < 4; r++) {
        int row = rowA0 + wr * 64 + m * 16 + (lane >> 4) * 4 + r;
        int col = colB0 + wc * 64 + n * 16 + (lane & 15);
        out[(int64_t)row * 512 + col] = acc[m][n][r] + bp[col];
      }
}

// ---------------- fused flash attention with distance-ALiBi bias -----------
// grid (64 qtiles, 16 bh), 256 thr = 4 waves x 16 q-rows, KVBLK=64
__global__ __launch_bounds__(256) void attn_kernel(
    const bf16* __restrict__ Qb, const bf16* __restrict__ Kb,
    const bf16* __restrict__ Vt, const float* __restrict__ coords,
    const float* __restrict__ slopes, bf16* __restrict__ Ob) {
  __shared__ __align__(128) char sK[8192];   // [64 kv][64 hd] swizzled
  __shared__ __align__(128) char sV[8192];   // [64 hd][64 kv] swizzled
  __shared__ __align__(16) float skc[128];   // 64 (x,y) k coords
  __shared__ __align__(128) char sP[4][2048];  // per-wave P tile [16][64] swz

  const int lane = threadIdx.x & 63, w = threadIdx.x >> 6;
  const int bh = blockIdx.y, b = bh >> 3, h = bh & 7;
  const int q0 = blockIdx.x * 64;
  const int qw = q0 + w * 16;
  const float slope = slopes[h];

  // Q fragments held in registers for the whole kernel
  bf16x8 aq[2];
  {
    int64_t base =
        ((int64_t)(b * 4096 + qw + (lane & 15))) * 512 + h * 64 + (lane >> 4) * 8;
    aq[0] = *(const bf16x8*)(Qb + base);
    aq[1] = *(const bf16x8*)(Qb + base + 32);
  }
  float qx[4], qy[4];
#pragma unroll
  for (int r = 0; r < 4; r++) {
    int64_t qi = (int64_t)b * 4096 + qw + (lane >> 4) * 4 + r;
    float2 c2 = ((const float2*)coords)[qi];
    qx[r] = c2.x;
    qy[r] = c2.y;
  }

  float mrun[4], lrun[4];
  f32x4 o[4];
#pragma unroll
  for (int r = 0; r < 4; r++) { mrun[r] = -1e30f; lrun[r] = 0.f; }
#pragma unroll
  for (int n = 0; n < 4; n++) o[n] = (f32x4){0.f, 0.f, 0.f, 0.f};

  const int lr = lane >> 3;
  const int kswz = 8 * ((lane & 7) ^ lr);
  char* pw = (char*)sP[w];

  for (int kv0 = 0; kv0 < 4096; kv0 += 64) {
    // stage K (row-major per head) and V (transposed [e][kv]) tiles
#pragma unroll
    for (int j = 0; j < 2; j++) {
      const int c = w * 2 + j;  // chunk 0..7
      gload16(Kb + ((int64_t)(b * 4096 + kv0 + c * 8 + lr)) * 512 + h * 64 + kswz,
              sK + c * 1024);
      gload16(Vt + ((int64_t)((b * 8 + h) * 64 + c * 8 + lr)) * 4096 + kv0 + kswz,
              sV + c * 1024);
    }
    if (threadIdx.x < 128)
      skc[threadIdx.x] = coords[((int64_t)b * 4096 + kv0) * 2 + threadIdx.x];
    __syncthreads();

    // S = Q K^T / 8 - slope*dist   (16 q-rows x 64 kv per wave)
    float s[4][4];
#pragma unroll
    for (int t = 0; t < 4; t++) {
      f32x4 sa = (f32x4){0.f, 0.f, 0.f, 0.f};
#pragma unroll
      for (int kk = 0; kk < 2; kk++) {
        bf16x8 kf = *(const bf16x8*)(sK + swz(t * 16 + (lane & 15),
                                              kk * 64 + (lane >> 4) * 16));
        sa = __builtin_amdgcn_mfma_f32_16x16x32_bf16(aq[kk], kf, sa, 0, 0, 0);
      }
      float2 kc2 = ((const float2*)skc)[t * 16 + (lane & 15)];
#pragma unroll
      for (int r = 0; r < 4; r++) {
        float dx = qx[r] - kc2.x, dy = qy[r] - kc2.y;
        s[t][r] = sa[r] * 0.125f - slope * sqrtf(dx * dx + dy * dy);
      }
    }

    // online softmax update
    float pm[4], scale[4], rs[4];
#pragma unroll
    for (int r = 0; r < 4; r++) {
      float v = fmaxf(fmaxf(s[0][r], s[1][r]), fmaxf(s[2][r], s[3][r]));
      pm[r] = redmax16(v);
      float mn = fmaxf(mrun[r], pm[r]);
      scale[r] = exp2f((mrun[r] - mn) * 1.4426950408889634f);
      mrun[r] = mn;
      rs[r] = 0.f;
    }
    float p[4][4];
#pragma unroll
    for (int t = 0; t < 4; t++)
#pragma unroll
      for (int r = 0; r < 4; r++) {
        p[t][r] = exp2f((s[t][r] - mrun[r]) * 1.4426950408889634f);
        rs[r] += p[t][r];
      }
#pragma unroll
    for (int r = 0; r < 4; r++) {
      rs[r] = redsum16(rs[r]);
      lrun[r] = lrun[r] * scale[r] + rs[r];
    }
#pragma unroll
    for (int n = 0; n < 4; n++)
#pragma unroll
      for (int r = 0; r < 4; r++) o[n][r] *= scale[r];

    // P -> per-wave LDS (swizzled), then read back as MFMA A-fragments
#pragma unroll
    for (int t = 0; t < 4; t++)
#pragma unroll
      for (int r = 0; r < 4; r++) {
        int row = (lane >> 4) * 4 + r, col = t * 16 + (lane & 15);
        *(bf16*)(pw + swz(row, col * 2)) = (bf16)p[t][r];
      }
    bf16x8 pa[2];
#pragma unroll
    for (int kk = 0; kk < 2; kk++)
      pa[kk] = *(const bf16x8*)(pw + swz(lane & 15, kk * 64 + (lane >> 4) * 16));
#pragma unroll
    for (int n = 0; n < 4; n++)
#pragma unroll
      for (int kk = 0; kk < 2; kk++) {
        bf16x8 vf = *(const bf16x8*)(sV + swz(n * 16 + (lane & 15),
                                              kk * 64 + (lane >> 4) * 16));
        o[n] = __builtin_amdgcn_mfma_f32_16x16x32_bf16(pa[kk], vf, o[n], 0, 0, 0);
      }
    __syncthreads();
  }

  // epilogue: normalize and store attention output in [b,n,d] bf16
#pragma unroll
  for (int r = 0; r < 4; r++) {
    float inv = 1.f / lrun[r];
    int64_t row = (int64_t)b * 4096 + qw + (lane >> 4) * 4 + r;
#pragma unroll
    for (int n = 0; n < 4; n++) {
      Ob[row * 512 + h * 64 + n * 16 + (lane & 15)] = (bf16)(o[n][r] * inv);
    }
  }
}

// ---------------- launch ---------------------------------------------------
extern "C" void kernel_launch(void* const* d_in, const int* in_sizes, int n_in,
                              void* d_out, int out_size, void* d_ws,
                              size_t ws_size, hipStream_t stream) {
  const float* x = (const float*)d_in[0];
  const float* coords = (const float*)d_in[1];
  const float* Wq = (const float*)d_in[2];
  const float* bq = (const float*)d_in[3];
  const float* Wk = (const float*)d_in[4];
  const float* bk = (const float*)d_in[5];
  const float* Wv = (const float*)d_in[6];
  const float* bv = (const float*)d_in[7];
  const float* Wp = (const float*)d_in[8];
  const float* bp = (const float*)d_in[9];
  const float* slopes = (const float*)d_in[10];

  char* ws = (char*)d_ws;
  bf16* xb = (bf16*)(ws);                       // 8192x512
  bf16* Wt = (bf16*)(ws + 8388608);             // 1536x512 (Wq|Wk|Wv transposed)
  bf16* Wpt = (bf16*)(ws + 9961472);            // 512x512 (Wp transposed)
  bf16* Qb = (bf16*)(ws + 10485760);            // 8192x512 [b,n,d]
  bf16* Kb = (bf16*)(ws + 18874368);            // 8192x512 [b,n,d]
  bf16* Vt = (bf16*)(ws + 27262976);            // [16 bh][64 e][4096 n]
  bf16* Ob = (bf16*)(ws + 35651584);            // 8192x512 [b,n,d]

  hipLaunchKernelGGL(prep_kernel, dim3(1024), dim3(256), 0, stream, x, Wq, Wk,
                     Wv, Wp, xb, Wt, Wpt);
  hipLaunchKernelGGL(qkv_gemm, dim3(12, 64), dim3(256), 0, stream, xb, Wt, bq,
                     bk, bv, Qb, Kb, Vt);
  hipLaunchKernelGGL(attn_kernel, dim3(64, 16), dim3(256), 0, stream, Qb, Kb,
                     Vt, coords, slopes, Ob);
  hipLaunchKernelGGL(out_gemm, dim3(4, 64), dim3(256), 0, stream, Ob, Wpt, bp,
                     (float*)d_out);
}

// Round 2
// 414.188 us; speedup vs baseline: 1.0674x; 1.0674x over previous
//
#include <hip/hip_runtime.h>
#include <stdint.h>

typedef __bf16 bf16;
typedef __attribute__((ext_vector_type(8))) __bf16 bf16x8;
typedef __attribute__((ext_vector_type(4))) __bf16 bf16x4;
typedef __attribute__((ext_vector_type(4))) float f32x4;

#define DEVFN static __device__ __forceinline__

DEVFN void gload16(const bf16* g, char* l) {
  __builtin_amdgcn_global_load_lds(
      (const __attribute__((address_space(1))) void*)g,
      (__attribute__((address_space(3))) void*)l, 16, 0, 0);
}

DEVFN int swz(int row, int kb) { return row * 128 + (kb ^ ((row & 7) << 4)); }

DEVFN float redmax16(float v) {
  v = fmaxf(v, __shfl_xor(v, 1));
  v = fmaxf(v, __shfl_xor(v, 2));
  v = fmaxf(v, __shfl_xor(v, 4));
  v = fmaxf(v, __shfl_xor(v, 8));
  return v;
}

// ---------------- prep: fp32 -> bf16 + weight transposes --------------------
__global__ __launch_bounds__(256) void prep_kernel(
    const float* __restrict__ x, const float* __restrict__ Wq,
    const float* __restrict__ Wk, const float* __restrict__ Wv,
    const float* __restrict__ Wp, bf16* __restrict__ xb,
    bf16* __restrict__ Wt, bf16* __restrict__ Wpt) {
  const int64_t tid = blockIdx.x * 256LL + threadIdx.x;
  const int64_t stride = (int64_t)gridDim.x * 256LL;
  for (int64_t i = tid; i < (8192LL * 512) / 4; i += stride) {
    float4 v = ((const float4*)x)[i];
    bf16x4 o = {(bf16)v.x, (bf16)v.y, (bf16)v.z, (bf16)v.w};
    ((bf16x4*)xb)[i] = o;
  }
  for (int64_t i = tid; i < 1536LL * 512; i += stride) {
    int c = (int)(i >> 9), k = (int)(i & 511);
    int wsel = c >> 9, cc = c & 511;
    const float* W = wsel == 0 ? Wq : (wsel == 1 ? Wk : Wv);
    Wt[i] = (bf16)W[k * 512 + cc];
  }
  for (int64_t i = tid; i < 512LL * 512; i += stride) {
    int c = (int)(i >> 9), k = (int)(i & 511);
    Wpt[i] = (bf16)Wp[k * 512 + c];
  }
}

// ---------------- shared 128x128 bf16 GEMM mainloop (K=512, BK=64) ----------
DEVFN void gemm_main(const bf16* __restrict__ A, const bf16* __restrict__ B,
                     int rowA0, int rowB0, char* sA, char* sB, f32x4 acc[4][4],
                     int wr, int wc, int lane, int w) {
#pragma unroll
  for (int m = 0; m < 4; m++)
#pragma unroll
    for (int n = 0; n < 4; n++) acc[m][n] = (f32x4){0.f, 0.f, 0.f, 0.f};
  const int lr = lane >> 3;
  const int kswz = 8 * ((lane & 7) ^ lr);
  for (int k0 = 0; k0 < 512; k0 += 64) {
#pragma unroll
    for (int j = 0; j < 4; j++) {
      const int c = w * 4 + j;
      gload16(A + (rowA0 + c * 8 + lr) * 512 + k0 + kswz, sA + c * 1024);
      gload16(B + (rowB0 + c * 8 + lr) * 512 + k0 + kswz, sB + c * 1024);
    }
    __syncthreads();
    bf16x8 af[4][2], bfv[4][2];
#pragma unroll
    for (int m = 0; m < 4; m++)
#pragma unroll
      for (int kk = 0; kk < 2; kk++) {
        af[m][kk] = *(const bf16x8*)(sA + swz(wr * 64 + m * 16 + (lane & 15),
                                              kk * 64 + (lane >> 4) * 16));
        bfv[m][kk] = *(const bf16x8*)(sB + swz(wc * 64 + m * 16 + (lane & 15),
                                               kk * 64 + (lane >> 4) * 16));
      }
#pragma unroll
    for (int m = 0; m < 4; m++)
#pragma unroll
      for (int n = 0; n < 4; n++)
#pragma unroll
        for (int kk = 0; kk < 2; kk++)
          acc[m][n] = __builtin_amdgcn_mfma_f32_16x16x32_bf16(
              af[m][kk], bfv[n][kk], acc[m][n], 0, 0, 0);
    __syncthreads();
  }
}

// ---------------- QKV projection ------------------------------------------
__global__ __launch_bounds__(256) void qkv_gemm(
    const bf16* __restrict__ xb, const bf16* __restrict__ Wt,
    const float* __restrict__ bq, const float* __restrict__ bk,
    const float* __restrict__ bv, bf16* __restrict__ Qb, bf16* __restrict__ Kb,
    bf16* __restrict__ Vt) {
  __shared__ __align__(128) char sA[16384];
  __shared__ __align__(128) char sB[16384];
  const int lane = threadIdx.x & 63, w = threadIdx.x >> 6;
  const int wr = w >> 1, wc = w & 1;
  const int rowA0 = blockIdx.y * 128;
  const int colB0 = blockIdx.x * 128;
  f32x4 acc[4][4];
  gemm_main(xb, Wt, rowA0, colB0, sA, sB, acc, wr, wc, lane, w);
  const int which = colB0 >> 9;
  const int cc0 = colB0 & 511;
  const float* bias = which == 0 ? bq : (which == 1 ? bk : bv);
#pragma unroll
  for (int m = 0; m < 4; m++)
#pragma unroll
    for (int n = 0; n < 4; n++)
#pragma unroll
      for (int r = 0; r < 4; r++) {
        int row = rowA0 + wr * 64 + m * 16 + (lane >> 4) * 4 + r;
        int col = cc0 + wc * 64 + n * 16 + (lane & 15);
        float v = acc[m][n][r] + bias[col];
        if (which == 0) {
          Qb[(int64_t)row * 512 + col] = (bf16)v;
        } else if (which == 1) {
          Kb[(int64_t)row * 512 + col] = (bf16)v;
        } else {
          int b = row >> 12, nn = row & 4095;
          int hh = col >> 6, e = col & 63;
          Vt[(((int64_t)(b * 8 + hh)) * 64 + e) * 4096 + nn] = (bf16)v;
        }
      }
}

// ---------------- output projection (fp32 out) ----------------------------
__global__ __launch_bounds__(256) void out_gemm(const bf16* __restrict__ Ob,
                                                const bf16* __restrict__ Wpt,
                                                const float* __restrict__ bp,
                                                float* __restrict__ out) {
  __shared__ __align__(128) char sA[16384];
  __shared__ __align__(128) char sB[16384];
  const int lane = threadIdx.x & 63, w = threadIdx.x >> 6;
  const int wr = w >> 1, wc = w & 1;
  const int rowA0 = blockIdx.y * 128;
  const int colB0 = blockIdx.x * 128;
  f32x4 acc[4][4];
  gemm_main(Ob, Wpt, rowA0, colB0, sA, sB, acc, wr, wc, lane, w);
#pragma unroll
  for (int m = 0; m < 4; m++)
#pragma unroll
    for (int n = 0; n < 4; n++)
#pragma unroll
      for (int r = 0; r < 4; r++) {
        int row = rowA0 + wr * 64 + m * 16 + (lane >> 4) * 4 + r;
        int col = colB0 + wc * 64 + n * 16 + (lane & 15);
        out[(int64_t)row * 512 + col] = acc[m][n][r] + bp[col];
      }
}

// ---------------- fused flash attention, multi-head dist sharing -----------
__global__ __launch_bounds__(256) void attn_kernel(
    const bf16* __restrict__ Qb, const bf16* __restrict__ Kb,
    const bf16* __restrict__ Vt, const float* __restrict__ coords,
    const float* __restrict__ slopes, bf16* __restrict__ Ob) {
  __shared__ float sdist[3][32 * 64];
  __shared__ __align__(128) char sP[4][2048];

  const int tid = threadIdx.x;
  const int lane = tid & 63, w = tid >> 6;
  const int c = lane & 15, g = lane >> 4;
  const int b = blockIdx.y;
  const int h = blockIdx.z * 4 + w;
  const int q0 = blockIdx.x * 32;

  const float LOG2E = 1.4426950408889634f;
  const float c1 = 0.125f * LOG2E;
  const float negsl2 = -slopes[h] * LOG2E;

  bf16x8 aq[2][2];
#pragma unroll
  for (int sub = 0; sub < 2; sub++) {
    int64_t base =
        ((int64_t)(b * 4096 + q0 + sub * 16 + c)) * 512 + h * 64 + g * 8;
    aq[sub][0] = *(const bf16x8*)(Qb + base);
    aq[sub][1] = *(const bf16x8*)(Qb + base + 32);
  }

  float qpx[8], qpy[8];
#pragma unroll
  for (int j = 0; j < 8; j++) {
    int q = (tid >> 6) + 4 * j;
    float2 c2 = ((const float2*)coords)[(int64_t)b * 4096 + q0 + q];
    qpx[j] = c2.x;
    qpy[j] = c2.y;
  }

  bf16x8 ones;
#pragma unroll
  for (int j = 0; j < 8; j++) ones[j] = (bf16)1.0f;

  float m2[2][4];
  f32x4 o[2][4], osum[2];
#pragma unroll
  for (int sub = 0; sub < 2; sub++) {
#pragma unroll
    for (int r = 0; r < 4; r++) m2[sub][r] = -1e30f;
#pragma unroll
    for (int n = 0; n < 4; n++) o[sub][n] = (f32x4){0.f, 0.f, 0.f, 0.f};
    osum[sub] = (f32x4){0.f, 0.f, 0.f, 0.f};
  }

  const bf16* Kp = Kb + (int64_t)b * 4096 * 512 + h * 64;
  const bf16* Vp = Vt + (int64_t)(b * 8 + h) * 64 * 4096;

  bf16x8 kf[4][2], vf[4][2];
#define LOADK(KV)                                                         \
  {                                                                       \
    _Pragma("unroll") for (int t = 0; t < 4; t++) _Pragma("unroll") for ( \
        int kk = 0; kk < 2; kk++) kf[t][kk] =                             \
        *(const bf16x8*)(Kp + (int64_t)((KV) + t * 16 + c) * 512 +        \
                         kk * 32 + g * 8);                                \
  }
#define LOADV(KV)                                                         \
  {                                                                       \
    _Pragma("unroll") for (int n = 0; n < 4; n++) _Pragma("unroll") for ( \
        int kk = 0; kk < 2; kk++) vf[n][kk] =                             \
        *(const bf16x8*)(Vp + (int64_t)(n * 16 + c) * 4096 + (KV) +       \
                         kk * 32 + g * 8);                                \
  }

  auto produce = [&](int buf, int kv0n) {
    int k = tid & 63;
    float2 kc = ((const float2*)coords)[(int64_t)b * 4096 + kv0n + k];
    float* db = sdist[buf];
#pragma unroll
    for (int j = 0; j < 8; j++) {
      float dx = qpx[j] - kc.x, dy = qpy[j] - kc.y;
      float d = __builtin_amdgcn_sqrtf(dx * dx + dy * dy);
      int q = (tid >> 6) + 4 * j;
      db[q * 64 + (k ^ ((j & 1) << 4))] = d;
    }
  };

  LOADK(0);
  LOADV(0);
  produce(0, 0);

  const int xm = (g & 1) << 4;
  char* pw = (char*)sP[w];
  int cb = 0;
  for (int i = 0; i < 64; i++) {
    int nb = cb + 1;
    if (nb == 3) nb = 0;
    if (i + 1 < 64) produce(nb, (i + 1) * 64);
    __syncthreads();
    const float* db = sdist[cb];
#pragma unroll
    for (int sub = 0; sub < 2; sub++) {
      float s[4][4];
#pragma unroll
      for (int t = 0; t < 4; t++) {
        f32x4 sa = (f32x4){0.f, 0.f, 0.f, 0.f};
        sa = __builtin_amdgcn_mfma_f32_16x16x32_bf16(aq[sub][0], kf[t][0], sa,
                                                     0, 0, 0);
        sa = __builtin_amdgcn_mfma_f32_16x16x32_bf16(aq[sub][1], kf[t][1], sa,
                                                     0, 0, 0);
#pragma unroll
        for (int r = 0; r < 4; r++) {
          float dv = db[(sub * 16 + g * 4 + r) * 64 + ((t * 16 + c) ^ xm)];
          s[t][r] = __builtin_fmaf(sa[r], c1, dv * negsl2);
        }
      }
      if (sub == 1 && i + 1 < 64) LOADK((i + 1) * 64);

      float lm[4];
#pragma unroll
      for (int r = 0; r < 4; r++)
        lm[r] = fmaxf(fmaxf(s[0][r], s[1][r]), fmaxf(s[2][r], s[3][r]));
      bool ex = lm[0] > m2[sub][0] + 8.f || lm[1] > m2[sub][1] + 8.f ||
                lm[2] > m2[sub][2] + 8.f || lm[3] > m2[sub][3] + 8.f;
      if (__any(ex)) {
#pragma unroll
        for (int r = 0; r < 4; r++) {
          float pm = redmax16(lm[r]);
          float nm = fmaxf(m2[sub][r], pm);
          float sc = __builtin_amdgcn_exp2f(m2[sub][r] - nm);
          m2[sub][r] = nm;
#pragma unroll
          for (int n = 0; n < 4; n++) o[sub][n][r] *= sc;
          osum[sub][r] *= sc;
        }
      }
#pragma unroll
      for (int t = 0; t < 4; t++)
#pragma unroll
        for (int r = 0; r < 4; r++) {
          float p = __builtin_amdgcn_exp2f(s[t][r] - m2[sub][r]);
          int row = g * 4 + r;
          *(bf16*)(pw + row * 128 + ((t * 32 + c * 2) ^ ((row & 7) << 4))) =
              (bf16)p;
        }
      bf16x8 pa0 = *(const bf16x8*)(pw + c * 128 + ((g * 16) ^ ((c & 7) << 4)));
      bf16x8 pa1 =
          *(const bf16x8*)(pw + c * 128 + ((64 + g * 16) ^ ((c & 7) << 4)));
#pragma unroll
      for (int n = 0; n < 4; n++) {
        o[sub][n] = __builtin_amdgcn_mfma_f32_16x16x32_bf16(pa0, vf[n][0],
                                                            o[sub][n], 0, 0, 0);
        o[sub][n] = __builtin_amdgcn_mfma_f32_16x16x32_bf16(pa1, vf[n][1],
                                                            o[sub][n], 0, 0, 0);
      }
      osum[sub] = __builtin_amdgcn_mfma_f32_16x16x32_bf16(pa0, ones, osum[sub],
                                                          0, 0, 0);
      osum[sub] = __builtin_amdgcn_mfma_f32_16x16x32_bf16(pa1, ones, osum[sub],
                                                          0, 0, 0);
    }
    if (i + 1 < 64) LOADV((i + 1) * 64);
    cb = nb;
  }

#pragma unroll
  for (int sub = 0; sub < 2; sub++)
#pragma unroll
    for (int r = 0; r < 4; r++) {
      float inv = 1.f / osum[sub][r];
      int64_t row = (int64_t)b * 4096 + q0 + sub * 16 + g * 4 + r;
#pragma unroll
      for (int n = 0; n < 4; n++)
        Ob[row * 512 + h * 64 + n * 16 + c] = (bf16)(o[sub][n][r] * inv);
    }
}

// ---------------- launch ---------------------------------------------------
extern "C" void kernel_launch(void* const* d_in, const int* in_sizes, int n_in,
                              void* d_out, int out_size, void* d_ws,
                              size_t ws_size, hipStream_t stream) {
  const float* x = (const float*)d_in[0];
  const float* coords = (const float*)d_in[1];
  const float* Wq = (const float*)d_in[2];
  const float* bq = (const float*)d_in[3];
  const float* Wk = (const float*)d_in[4];
  const float* bk = (const float*)d_in[5];
  const float* Wv = (const float*)d_in[6];
  const float* bv = (const float*)d_in[7];
  const float* Wp = (const float*)d_in[8];
  const float* bp = (const float*)d_in[9];
  const float* slopes = (const float*)d_in[10];

  char* ws = (char*)d_ws;
  bf16* xb = (bf16*)(ws);
  bf16* Wt = (bf16*)(ws + 8388608);
  bf16* Wpt = (bf16*)(ws + 9961472);
  bf16* Qb = (bf16*)(ws + 10485760);
  bf16* Kb = (bf16*)(ws + 18874368);
  bf16* Vt = (bf16*)(ws + 27262976);
  bf16* Ob = (bf16*)(ws + 35651584);

  hipLaunchKernelGGL(prep_kernel, dim3(1024), dim3(256), 0, stream, x, Wq, Wk,
                     Wv, Wp, xb, Wt, Wpt);
  hipLaunchKernelGGL(qkv_gemm, dim3(12, 64), dim3(256), 0, stream, xb, Wt, bq,
                     bk, bv, Qb, Kb, Vt);
  hipLaunchKernelGGL(attn_kernel, dim3(128, 2, 2), dim3(256), 0, stream, Qb,
                     Kb, Vt, coords, slopes, Ob);
  hipLaunchKernelGGL(out_gemm, dim3(4, 64), dim3(256), 0, stream, Ob, Wpt, bp,
                     (float*)d_out);
}